// Round 6
// baseline (114.095 us; speedup 1.0000x reference)
//
#include <hip/hip_runtime.h>
#include <cstdint>

constexpr int BTOT  = 1048576;
constexpr int LCLS  = 81;
constexpr int GRP   = 9;
constexpr int ROWS  = 64;                    // rows per tile == threads per block (1 wave)
constexpr int THR   = 64;
constexpr int NTILE = BTOT / ROWS;           // 16384 tiles
constexpr int NBLKP = 768;                   // persistent blocks: 3 per CU x 256
constexpr int TILEF = ROWS * LCLS;           // 5184 floats = 20,736 B per tile
constexpr int TILE4 = TILEF / 4;             // 1296 float4
constexpr int FULLR = TILE4 / THR;           // 20 full staging rounds
constexpr int TAIL  = TILE4 - FULLR * THR;   // 16 leftover float4
constexpr float FIX = 67108864.0f;           // 2^26 fixed-point scale for loss

// Async global->LDS, 16B per lane, no VGPR round-trip (m97 pattern).
__device__ __forceinline__ void gload_lds16(const float* gsrc, float* ldst) {
    __builtin_amdgcn_global_load_lds(
        (const __attribute__((address_space(1))) void*)gsrc,
        (__attribute__((address_space(3))) void*)ldst,
        16, 0, 0);
}

// Issue one tile's 21 DMA ops (uniform per wave: lanes 0-15 take the tail).
__device__ __forceinline__ void stage_tile(const float* gt, float* buf, int tid) {
    #pragma unroll
    for (int r = 0; r < FULLR; ++r) {
        const int i = r * THR + tid;
        gload_lds16(gt + 4 * i, &buf[4 * i]);
    }
    if (tid < TAIL) {
        const int i = FULLR * THR + tid;
        gload_lds16(gt + 4 * i, &buf[4 * i]);
    }
}

// Rare knife-edge path (~1e-5 of rows): group argmax in f64 from the LDS row.
__device__ __attribute__((noinline)) int refine_group_f64(const float* __restrict__ xrow)
{
    double best = -1.0; int bi = 0;
    #pragma unroll
    for (int g = 0; g < GRP; ++g) {
        double s = 0.0;
        #pragma unroll
        for (int j = 0; j < GRP; ++j) s += exp((double)xrow[g * GRP + j]);
        if (s > best) { best = s; bi = g; }
    }
    return bi;
}

__global__ __launch_bounds__(THR) void hl_main(
    const float* __restrict__ x, const int* __restrict__ tgt,
    float* __restrict__ out, unsigned long long* __restrict__ acc)
{
    __shared__ float buf0[TILEF];            // 20,736 B
    __shared__ float buf1[TILEF];            // 20,736 B  -> 3 blocks/CU
    const int tid = threadIdx.x;

    unsigned long long lqT = 0;
    unsigned dT = 0;

    int tile = blockIdx.x;
    stage_tile(x + (size_t)tile * TILEF, buf0, tid);   // prologue: tile0 -> buf0

    int cur = 0;
    for (; tile < NTILE; tile += NBLKP) {
        const int row  = tile * ROWS + tid;
        const int t    = tgt[row];                       // 1 VMEM load
        const int next = tile + NBLKP;

        // issue next tile into the other buffer BEFORE waiting on current
        if (next < NTILE)
            stage_tile(x + (size_t)next * TILEF, (cur == 0) ? buf1 : buf0, tid); // 21 VMEM

        // counted wait: retire current tile's 21 DMAs, keep next tile in flight.
        // window audit: ops newer than current tile's stage = prev store(1) +
        // tgt(1) + next stage(21) -> vmcnt(22) safe (prologue window = 22 exactly).
        if (next < NTILE) {
            asm volatile("s_waitcnt vmcnt(22)" ::: "memory");
        } else {
            asm volatile("s_waitcnt vmcnt(2)" ::: "memory");   // leave tgt/store in flight
        }
        __builtin_amdgcn_sched_barrier(0);

        const float* xr = ((cur == 0) ? buf0 : buf1) + tid * LCLS;  // stride-81: 2-way alias, free

        // ---- group exp-sums (fast __expf: err ~3e-7 << 1e-5 refine guard) ----
        float gs[GRP];
        #pragma unroll
        for (int g = 0; g < GRP; ++g) {
            float s = 0.0f;
            #pragma unroll
            for (int j = 0; j < GRP; ++j) s += __expf(xr[g * GRP + j]);
            gs[g] = s;
        }
        float S = gs[0];
        #pragma unroll
        for (int g = 1; g < GRP; ++g) S += gs[g];

        // group argmax, top-2 tracked (strict >, first index wins)
        float g1 = gs[0], g2 = -1e30f; int gi = 0;
        #pragma unroll
        for (int g = 1; g < GRP; ++g) {
            float v = gs[g];
            bool gt2 = v > g1;
            g2 = gt2 ? g1 : (v > g2 ? v : g2);
            g1 = gt2 ? v  : g1;
            gi = gt2 ? g  : gi;
        }

        const int parent = t / GRP;
        float gpar = gs[0];
        #pragma unroll
        for (int g = 1; g < GRP; ++g)
            gpar = (parent == g) ? gs[g] : gpar;         // static-index select chain

        if (g1 - g2 < 1e-5f * g1) gi = refine_group_f64(xr);

        // within-group argmax on RAW x — exp/softmax monotonic, so EXACT
        const int wb = gi * GRP;
        float w1 = xr[wb]; int wi = 0;
        #pragma unroll
        for (int j = 1; j < GRP; ++j) {
            float v = xr[wb + j];
            if (v > w1) { w1 = v; wi = j; }
        }

        const int pred = gi * GRP + wi;

        float et  = expf(xr[t]);                          // precise ocml exp, once/row
        float win = 0.5f * (gpar + et) / S;
        float nl  = -logf(win);
        lqT += (unsigned long long)llrintf(nl * FIX);
        dT  += (pred == t) ? 0u : ((gi == parent) ? 1u : 2u);

        out[1 + row] = (float)pred;                       // 1 VMEM store
        cur ^= 1;
    }

    // ---- deterministic wave reduction + device-scope integer atomics ----
    #pragma unroll
    for (int off = 32; off > 0; off >>= 1) {
        lqT += __shfl_down(lqT, off);
        dT  += __shfl_down(dT, off);
    }
    if (tid == 0) {
        atomicAdd(&acc[0], lqT);
        atomicAdd(&acc[1], (unsigned long long)dT);
        __threadfence();
        unsigned* tick = (unsigned*)(acc + 2);
        unsigned old = atomicAdd(tick, 1u);
        if (old == (unsigned)(NBLKP - 1)) {               // last block finalizes
            __threadfence();
            unsigned long long ta = atomicAdd(&acc[0], 0ull);
            unsigned long long tb = atomicAdd(&acc[1], 0ull);
            out[0] = (float)(((double)ta / 67108864.0) / (double)BTOT);
            out[1 + BTOT] = (float)tb;
        }
    }
}

extern "C" void kernel_launch(void* const* d_in, const int* in_sizes, int n_in,
                              void* d_out, int out_size, void* d_ws, size_t ws_size,
                              hipStream_t stream) {
    const float* outputs = (const float*)d_in[0];
    const int*   target  = (const int*)d_in[1];
    float* out = (float*)d_out;
    unsigned long long* acc = (unsigned long long*)d_ws;  // [loss_q, dist, ticket] = 24 B

    hipMemsetAsync(d_ws, 0, 24, stream);                  // re-zero accumulators every call
    hl_main<<<NBLKP, THR, 0, stream>>>(outputs, target, out, acc);
}